// Round 10
// baseline (1613.920 us; speedup 1.0000x reference)
//
#include <hip/hip_runtime.h>
#include <math.h>

// Problem constants
#define NB   4        // batch
#define NH   16       // heads
#define DHD  64       // head dim
#define SL   2048     // Lq == Lk
#define DM   1024     // model dim
#define TOPK 205      // ceil(2048 * 0.1)

#define S_PER_BH 4194304   // 2048*2048 floats per (b,h) plane

// Scores are written in log2 domain: logit2 = (q.k) * 0.25 * log2(e).
#define SCALE_LOG2 0.36067376022224085f
#define MASK_LOG2  (-28853.900808f)

// ws layout (bytes), fixed part (identical to the measured round-4 kernel):
//  QH  bf16 head-major [B,H,L,DH] : 16MB @ 0
//  QL                              : 16MB @ 16MB
//  KH                              : 16MB @ 32MB
//  KL                              : 16MB @ 48MB
//  VTH bf16 transposed [B,H,DH,L]  : 16MB @ 64MB
//  VTL                             : 16MB @ 80MB
//  CTXH bf16 [B,L,D]               : 16MB @ 96MB
//  CTXL                            : 16MB @ 112MB
//  S   f32/packed [chunk,L,L]      : adaptive @ 128MB
// transient overlays (dead-region reuse, stream-ordered):
//  Xq split   -> 64..96MB  (consumed by gemm Q before gemm V writes VT)
//  Xk split   -> 96..128MB (consumed by gemm K/V before av writes CTX)
//  Wq/Wk/Wv   -> 128..140MB (consumed by gemms before scores writes S)
//  Wo split   -> 128..132MB (written AFTER attention loop, S is dead)

typedef unsigned short u16;
typedef short    bf16x8  __attribute__((ext_vector_type(8)));
typedef float    f32x4   __attribute__((ext_vector_type(4)));
typedef u16      ushort8 __attribute__((ext_vector_type(8)));
typedef u16      ushort4v __attribute__((ext_vector_type(4)));

// Round-to-nearest-even float -> bf16 split: x ~= hi + lo, both bf16.
__device__ inline void split2(float x, u16& h, u16& l)
{
    unsigned u = __float_as_uint(x);
    unsigned r = u + 0x7FFF + ((u >> 16) & 1);
    u16 hs = (u16)(r >> 16);
    float hf = __uint_as_float((unsigned)hs << 16);
    float lf = x - hf;
    unsigned ul = __float_as_uint(lf);
    unsigned rl = ul + 0x7FFF + ((ul >> 16) & 1);
    h = hs;
    l = (u16)(rl >> 16);
}

// ---------------------------------------------------------------------------
// Bulk fp32 -> split-bf16 conversion (one-time per tensor).
// ---------------------------------------------------------------------------
__global__ __launch_bounds__(256) void split_f32(const float* __restrict__ in,
                                                 u16* __restrict__ oh,
                                                 u16* __restrict__ ol,
                                                 int n4)
{
    const int stride = gridDim.x * 256;
    for (int i = blockIdx.x * 256 + threadIdx.x; i < n4; i += stride) {
        float4 v = ((const float4*)in)[i];
        u16 h0, l0, h1, l1, h2, l2, h3, l3;
        split2(v.x, h0, l0);
        split2(v.y, h1, l1);
        split2(v.z, h2, l2);
        split2(v.w, h3, l3);
        ushort4v h = { h0, h1, h2, h3 };
        ushort4v l = { l0, l1, l2, l3 };
        *(ushort4v*)&oh[(size_t)i * 4] = h;
        *(ushort4v*)&ol[(size_t)i * 4] = l;
    }
}

// ---------------------------------------------------------------------------
// Projection GEMM, pre-split operands: out = X @ W^T + bias.
// A = XH/XL [M,1024] u16 row-major; B = WH/WL [N,1024] u16 row-major.
// D += Ah*Bh + Ah*Bl + Al*Bh  (ll dropped; rel err ~2^-17).
// 64x128 tile (M x N), BK=32, 256 threads = 4 waves, each wave 32x64.
// Grid (8, 128) = 1024 blocks -> 4 blocks/CU, 16 waves/CU (occupancy fix:
// the old 128x128/512-block version ran 2 blocks/CU, 18% occupancy,
// MfmaUtil 24% with HBM at 10% -- grid-starved, not BW/compute bound).
// XCD-aware chunked block swizzle (1024 % 8 == 0 -> bijective).
// mode 0: head-major split write; 1: tanh + transposed split write (V^T);
// mode 2: fp32 [M,N] write.
// ---------------------------------------------------------------------------
__global__ __launch_bounds__(256) void gemm_mfma(const u16* __restrict__ XH,
                                                 const u16* __restrict__ XL,
                                                 const u16* __restrict__ WH,
                                                 const u16* __restrict__ WL,
                                                 const float* __restrict__ bias,
                                                 float* __restrict__ outF,
                                                 u16* __restrict__ outH,
                                                 u16* __restrict__ outL,
                                                 int mode)
{
    __shared__ u16 Ah[64 * 40];
    __shared__ u16 Al[64 * 40];
    __shared__ u16 Bh[128 * 40];
    __shared__ u16 Bl[128 * 40];

    const int t    = threadIdx.x;
    const int lane = t & 63;
    const int wv   = t >> 6;
    const int wm   = (wv & 1) * 32;   // wave M sub-tile 0/32
    const int wn   = (wv >> 1) * 64;  // wave N sub-tile 0/64

    // XCD swizzle: give each XCD a contiguous run of panels for L2 reuse.
    const int lin  = blockIdx.x + (int)gridDim.x * blockIdx.y;   // 0..1023
    const int per  = ((int)gridDim.x * (int)gridDim.y) >> 3;     // 128
    const int swz  = (lin & 7) * per + (lin >> 3);
    const int n0   = (swz & 7) * 128;       // gridDim.x == 8
    const int m0   = (swz >> 3) * 64;

    const int ra   = t >> 1;          // B staging row 0..127
    const int ca   = (t & 1) * 16;    // B staging col base 0/16
    const int raA  = t >> 2;          // A staging row 0..63
    const int caA  = (t & 3) * 8;     // A staging col base 0/8/16/24

    const u16* XHp = XH + (size_t)(m0 + raA) * DM + caA;
    const u16* XLp = XL + (size_t)(m0 + raA) * DM + caA;
    const u16* WHp = WH + (size_t)(n0 + ra) * DM + ca;
    const u16* WLp = WL + (size_t)(n0 + ra) * DM + ca;

    f32x4 acc[2][4] = {};

    const int lm   = lane & 15;
    const int koff = (lane >> 4) * 8;

    for (int kb = 0; kb < DM; kb += 32) {
        ushort8 xh0 = *(const ushort8*)(XHp + kb);
        ushort8 xl0 = *(const ushort8*)(XLp + kb);
        ushort8 wh0 = *(const ushort8*)(WHp + kb);
        ushort8 wh1 = *(const ushort8*)(WHp + kb + 8);
        ushort8 wl0 = *(const ushort8*)(WLp + kb);
        ushort8 wl1 = *(const ushort8*)(WLp + kb + 8);
        __syncthreads();   // previous iteration's readers done
        *(ushort8*)&Ah[raA * 40 + caA]   = xh0;
        *(ushort8*)&Al[raA * 40 + caA]   = xl0;
        *(ushort8*)&Bh[ra * 40 + ca]     = wh0;
        *(ushort8*)&Bh[ra * 40 + ca + 8] = wh1;
        *(ushort8*)&Bl[ra * 40 + ca]     = wl0;
        *(ushort8*)&Bl[ra * 40 + ca + 8] = wl1;
        __syncthreads();
        bf16x8 a_h[2], a_l[2], b_h[4], b_l[4];
        #pragma unroll
        for (int i = 0; i < 2; ++i) {
            int idx = (wm + i * 16 + lm) * 40 + koff;
            a_h[i] = *(const bf16x8*)&Ah[idx];
            a_l[i] = *(const bf16x8*)&Al[idx];
        }
        #pragma unroll
        for (int j = 0; j < 4; ++j) {
            int jdx = (wn + j * 16 + lm) * 40 + koff;
            b_h[j] = *(const bf16x8*)&Bh[jdx];
            b_l[j] = *(const bf16x8*)&Bl[jdx];
        }
        #pragma unroll
        for (int i = 0; i < 2; ++i)
            #pragma unroll
            for (int j = 0; j < 4; ++j) {
                acc[i][j] = __builtin_amdgcn_mfma_f32_16x16x32_bf16(
                    a_h[i], b_h[j], acc[i][j], 0, 0, 0);
                acc[i][j] = __builtin_amdgcn_mfma_f32_16x16x32_bf16(
                    a_h[i], b_l[j], acc[i][j], 0, 0, 0);
                acc[i][j] = __builtin_amdgcn_mfma_f32_16x16x32_bf16(
                    a_l[i], b_h[j], acc[i][j], 0, 0, 0);
            }
    }

    // ---- epilogue: C/D layout col=lane&15 (n), row=(lane>>4)*4+r (m) ----
    const int rq = (lane >> 4) * 4;
    #pragma unroll
    for (int j = 0; j < 4; ++j) {
        int n = n0 + wn + j * 16 + lm;
        float bb = bias[n];
        #pragma unroll
        for (int i = 0; i < 2; ++i) {
            #pragma unroll
            for (int r = 0; r < 4; ++r) {
                int m = m0 + wm + i * 16 + rq + r;
                float v = acc[i][j][r] + bb;
                if (mode == 2) {
                    outF[(size_t)m * DM + n] = v;
                } else {
                    int b = m >> 11, l = m & 2047, hh = n >> 6, d = n & 63;
                    size_t idx;
                    if (mode == 1) {
                        v = tanhf(v);
                        idx = ((size_t)(b * NH + hh) * DHD + d) * SL + l;   // V^T
                    } else {
                        idx = ((size_t)(b * NH + hh) * SL + l) * DHD + d;
                    }
                    u16 h_, l_;
                    split2(v, h_, l_);
                    outH[idx] = h_;
                    outL[idx] = l_;
                }
            }
        }
    }
}

// ---------------------------------------------------------------------------
// Scores via split-bf16 MFMA: S[z,q,k] = log2e*0.25 * Q.K ; masked -> -28854.
// (log2 domain so softmax can use native exp2.)
// 128x128 tile, full DH=64 as two BK=32 steps, grid (16,16,chunk).
// ---------------------------------------------------------------------------
__global__ __launch_bounds__(256) void scores_mfma(const u16* __restrict__ QH,
                                                   const u16* __restrict__ QL,
                                                   const u16* __restrict__ KH,
                                                   const u16* __restrict__ KL,
                                                   const int* __restrict__ mask,
                                                   float* __restrict__ S,
                                                   int bh0)
{
    __shared__ u16 Qhs[128 * 40];
    __shared__ u16 Qls[128 * 40];
    __shared__ u16 Khs[128 * 40];
    __shared__ u16 Kls[128 * 40];

    const int t    = threadIdx.x;
    const int lane = t & 63;
    const int wv   = t >> 6;
    const int wm   = (wv & 1) * 64;
    const int wn   = (wv >> 1) * 64;
    const int k0   = blockIdx.x * 128;
    const int q0   = blockIdx.y * 128;
    const int bhid = bh0 + blockIdx.z;

    const int row = t >> 1;          // 0..127
    const int col = (t & 1) * 16;    // 0/16
    const size_t qg = ((size_t)bhid * SL + q0 + row) * DHD + col;
    const size_t kg = ((size_t)bhid * SL + k0 + row) * DHD + col;

    f32x4 acc[4][4] = {};
    const int lm = lane & 15;
    const int ko = (lane >> 4) * 8;

    #pragma unroll
    for (int s = 0; s < 2; ++s) {
        ushort8 qh0 = *(const ushort8*)&QH[qg + s * 32];
        ushort8 qh1 = *(const ushort8*)&QH[qg + s * 32 + 8];
        ushort8 ql0 = *(const ushort8*)&QL[qg + s * 32];
        ushort8 ql1 = *(const ushort8*)&QL[qg + s * 32 + 8];
        ushort8 kh0 = *(const ushort8*)&KH[kg + s * 32];
        ushort8 kh1 = *(const ushort8*)&KH[kg + s * 32 + 8];
        ushort8 kl0 = *(const ushort8*)&KL[kg + s * 32];
        ushort8 kl1 = *(const ushort8*)&KL[kg + s * 32 + 8];
        __syncthreads();
        *(ushort8*)&Qhs[row * 40 + col]     = qh0;
        *(ushort8*)&Qhs[row * 40 + col + 8] = qh1;
        *(ushort8*)&Qls[row * 40 + col]     = ql0;
        *(ushort8*)&Qls[row * 40 + col + 8] = ql1;
        *(ushort8*)&Khs[row * 40 + col]     = kh0;
        *(ushort8*)&Khs[row * 40 + col + 8] = kh1;
        *(ushort8*)&Kls[row * 40 + col]     = kl0;
        *(ushort8*)&Kls[row * 40 + col + 8] = kl1;
        __syncthreads();
        bf16x8 ah[4], al[4], bh_[4], bl_[4];
        #pragma unroll
        for (int i = 0; i < 4; ++i) {
            int idx = (wm + i * 16 + lm) * 40 + ko;
            ah[i] = *(const bf16x8*)&Qhs[idx];
            al[i] = *(const bf16x8*)&Qls[idx];
        }
        #pragma unroll
        for (int j = 0; j < 4; ++j) {
            int jdx = (wn + j * 16 + lm) * 40 + ko;
            bh_[j] = *(const bf16x8*)&Khs[jdx];
            bl_[j] = *(const bf16x8*)&Kls[jdx];
        }
        #pragma unroll
        for (int i = 0; i < 4; ++i)
            #pragma unroll
            for (int j = 0; j < 4; ++j) {
                acc[i][j] = __builtin_amdgcn_mfma_f32_16x16x32_bf16(
                    ah[i], bh_[j], acc[i][j], 0, 0, 0);
                acc[i][j] = __builtin_amdgcn_mfma_f32_16x16x32_bf16(
                    ah[i], bl_[j], acc[i][j], 0, 0, 0);
                acc[i][j] = __builtin_amdgcn_mfma_f32_16x16x32_bf16(
                    al[i], bh_[j], acc[i][j], 0, 0, 0);
            }
    }

    const int rq = (lane >> 4) * 4;
    const int b  = bhid >> 4;
    const size_t zbase = (size_t)blockIdx.z * SL;
    #pragma unroll
    for (int j = 0; j < 4; ++j) {
        int k = k0 + wn + j * 16 + lm;
        int mk = mask[(size_t)b * SL + k];
        #pragma unroll
        for (int i = 0; i < 4; ++i) {
            #pragma unroll
            for (int r = 0; r < 4; ++r) {
                int q = q0 + wm + i * 16 + rq + r;
                float val = mk ? MASK_LOG2 : acc[i][j][r] * SCALE_LOG2;
                S[(zbase + q) * SL + k] = val;
            }
        }
    }
}

// ---------------------------------------------------------------------------
// Softmax (log2 domain, native exp2) + exact top-k threshold mask; writes
// packed split-bf16 (hi<<16|lo) in place over S.
// One row per wave; row cached in 32 VGPRs.  The exact k-th-value bitwise
// binary search counts via ballot+popcount (1 VALU cmp + scalar bcnt per
// value; no cross-lane shuffle reduce) -- count lands wave-uniform in SGPR.
// ---------------------------------------------------------------------------
__global__ __launch_bounds__(256) void softmax_topk(float* __restrict__ S)
{
    const int wave = threadIdx.x >> 6;
    const int lane = threadIdx.x & 63;
    const size_t row = (size_t)blockIdx.x * 4 + wave;
    float4* Sr = (float4*)(S + row * SL);               // 512 float4

    float4 v[8];
    #pragma unroll
    for (int i = 0; i < 8; ++i) v[i] = Sr[lane + 64 * i];

    float m = -1e30f;
    #pragma unroll
    for (int i = 0; i < 8; ++i)
        m = fmaxf(m, fmaxf(fmaxf(v[i].x, v[i].y), fmaxf(v[i].z, v[i].w)));
    #pragma unroll
    for (int o = 32; o > 0; o >>= 1) m = fmaxf(m, __shfl_xor(m, o, 64));

    float sum = 0.0f;
    #pragma unroll
    for (int i = 0; i < 8; ++i) {
        v[i].x = exp2f(v[i].x - m); v[i].y = exp2f(v[i].y - m);
        v[i].z = exp2f(v[i].z - m); v[i].w = exp2f(v[i].w - m);
        sum += (v[i].x + v[i].y) + (v[i].z + v[i].w);
    }
    #pragma unroll
    for (int o = 32; o > 0; o >>= 1) sum += __shfl_xor(sum, o, 64);
    float inv = 1.0f / sum;
    #pragma unroll
    for (int i = 0; i < 8; ++i) {
        v[i].x *= inv; v[i].y *= inv; v[i].z *= inv; v[i].w *= inv;
    }

    unsigned lo = 0u, hi = __float_as_uint(inv);
    while (lo < hi) {
        unsigned mid = (lo + hi + 1u) >> 1;
        int cnt = 0;
        #pragma unroll
        for (int i = 0; i < 8; ++i) {
            cnt += (int)__popcll(__ballot(__float_as_uint(v[i].x) >= mid));
            cnt += (int)__popcll(__ballot(__float_as_uint(v[i].y) >= mid));
            cnt += (int)__popcll(__ballot(__float_as_uint(v[i].z) >= mid));
            cnt += (int)__popcll(__ballot(__float_as_uint(v[i].w) >= mid));
        }
        if (cnt >= TOPK) lo = mid; else hi = mid - 1u;
    }

    #pragma unroll
    for (int i = 0; i < 8; ++i) {
        float4 x = v[i];
        x.x = (__float_as_uint(x.x) >= lo) ? x.x : 0.0f;
        x.y = (__float_as_uint(x.y) >= lo) ? x.y : 0.0f;
        x.z = (__float_as_uint(x.z) >= lo) ? x.z : 0.0f;
        x.w = (__float_as_uint(x.w) >= lo) ? x.w : 0.0f;
        u16 h_, l_;
        uint4 pk;
        split2(x.x, h_, l_); pk.x = ((unsigned)h_ << 16) | l_;
        split2(x.y, h_, l_); pk.y = ((unsigned)h_ << 16) | l_;
        split2(x.z, h_, l_); pk.z = ((unsigned)h_ << 16) | l_;
        split2(x.w, h_, l_); pk.w = ((unsigned)h_ << 16) | l_;
        *(uint4*)&Sr[lane + 64 * i] = pk;
    }
}

// ---------------------------------------------------------------------------
// AV via split-bf16 MFMA: CTX[b,q,h*64+d] = (sum_k attn*V) * gate(Q).
// 512 threads = 8 waves; block = 32q x 64d, each wave 16q x 16d; BK=64.
// Output written pre-split (CTXH/CTXL) for the Wo GEMM.
// ---------------------------------------------------------------------------
__global__ __launch_bounds__(512) void av_mfma(const unsigned int* __restrict__ SA,
                                               const u16* __restrict__ VTH,
                                               const u16* __restrict__ VTL,
                                               const u16* __restrict__ QH,
                                               const u16* __restrict__ QL,
                                               u16* __restrict__ CTXH,
                                               u16* __restrict__ CTXL,
                                               int bh0)
{
    __shared__ u16 Ahs[32 * 72];
    __shared__ u16 Als[32 * 72];
    __shared__ u16 Bhs[64 * 72];
    __shared__ u16 Bls[64 * 72];

    const int t    = threadIdx.x;
    const int lane = t & 63;
    const int wv   = t >> 6;          // 0..7
    const int wm   = (wv & 1) * 16;   // q sub-tile 0/16
    const int wn   = (wv >> 1) * 16;  // d sub-tile 0/16/32/48
    const int q0   = blockIdx.x * 32;
    const int z    = blockIdx.y;
    const int bhid = bh0 + z;
    const int b    = bhid >> 4, hh = bhid & 15;

    const int arow = t >> 4;          // 0..31 (q)
    const int acol = (t & 15) * 4;    // 0..60 (k, u32 granules)
    const int brow = t >> 3;          // 0..63 (d)
    const int bcol = (t & 7) * 8;     // 0..56 (k)

    const unsigned int* Sp = SA + ((size_t)z * SL + q0 + arow) * SL + acol;
    const u16* Vhp = VTH + ((size_t)bhid * DHD + brow) * SL + bcol;
    const u16* Vlp = VTL + ((size_t)bhid * DHD + brow) * SL + bcol;

    const int lm = lane & 15;
    const int ko = (lane >> 4) * 8;

    f32x4 acc = {};

    for (int kb = 0; kb < SL; kb += 64) {
        uint4 ua = *(const uint4*)(Sp + kb);
        ushort8 vh = *(const ushort8*)(Vhp + kb);
        ushort8 vl = *(const ushort8*)(Vlp + kb);
        __syncthreads();   // previous iteration's readers done
        ushort4v h0 = { (u16)(ua.x >> 16), (u16)(ua.y >> 16),
                        (u16)(ua.z >> 16), (u16)(ua.w >> 16) };
        ushort4v l0 = { (u16)ua.x, (u16)ua.y, (u16)ua.z, (u16)ua.w };
        *(ushort4v*)&Ahs[arow * 72 + acol] = h0;
        *(ushort4v*)&Als[arow * 72 + acol] = l0;
        *(ushort8*)&Bhs[brow * 72 + bcol]  = vh;
        *(ushort8*)&Bls[brow * 72 + bcol]  = vl;
        __syncthreads();
        #pragma unroll
        for (int s = 0; s < 2; ++s) {
            int ao = (wm + lm) * 72 + s * 32 + ko;
            bf16x8 a_h = *(const bf16x8*)&Ahs[ao];
            bf16x8 a_l = *(const bf16x8*)&Als[ao];
            int bo = (wn + lm) * 72 + s * 32 + ko;
            bf16x8 b_h = *(const bf16x8*)&Bhs[bo];
            bf16x8 b_l = *(const bf16x8*)&Bls[bo];
            acc = __builtin_amdgcn_mfma_f32_16x16x32_bf16(a_h, b_h, acc, 0, 0, 0);
            acc = __builtin_amdgcn_mfma_f32_16x16x32_bf16(a_h, b_l, acc, 0, 0, 0);
            acc = __builtin_amdgcn_mfma_f32_16x16x32_bf16(a_l, b_h, acc, 0, 0, 0);
        }
    }

    const int rq = (lane >> 4) * 4;
    const int d  = wn + lm;
    #pragma unroll
    for (int r = 0; r < 4; ++r) {
        int q = q0 + wm + rq + r;
        size_t gi = ((size_t)bhid * SL + q) * DHD + d;
        float gf = __uint_as_float((unsigned)QH[gi] << 16)
                 + __uint_as_float((unsigned)QL[gi] << 16);
        float cv = acc[r] * gf;
        u16 h_, l_;
        split2(cv, h_, l_);
        size_t ci = ((size_t)b * SL + q) * DM + hh * DHD + d;
        CTXH[ci] = h_;
        CTXL[ci] = l_;
    }
}

// ---------------------------------------------------------------------------
extern "C" void kernel_launch(void* const* d_in, const int* in_sizes, int n_in,
                              void* d_out, int out_size, void* d_ws, size_t ws_size,
                              hipStream_t stream)
{
    const float* q_in = (const float*)d_in[0];
    const float* k_in = (const float*)d_in[1];
    const float* Wq   = (const float*)d_in[2];
    const float* bq   = (const float*)d_in[3];
    const float* Wk   = (const float*)d_in[4];
    const float* bk   = (const float*)d_in[5];
    const float* Wv   = (const float*)d_in[6];
    const float* bv   = (const float*)d_in[7];
    const float* Wo   = (const float*)d_in[8];
    const float* bo   = (const float*)d_in[9];
    const int*   mask = (const int*)d_in[10];   // bool -> int32 per harness
    float* out = (float*)d_out;

    char* wsb = (char*)d_ws;
    const size_t MB = 1024 * 1024;
    u16* QHp  = (u16*)(wsb);
    u16* QLp  = (u16*)(wsb + 16 * MB);
    u16* KHp  = (u16*)(wsb + 32 * MB);
    u16* KLp  = (u16*)(wsb + 48 * MB);
    u16* VTHp = (u16*)(wsb + 64 * MB);
    u16* VTLp = (u16*)(wsb + 80 * MB);
    u16* CTXH = (u16*)(wsb + 96 * MB);
    u16* CTXL = (u16*)(wsb + 112 * MB);
    float* S  = (float*)(wsb + 128 * MB);

    // Transient overlays (see layout comment).
    u16* XqH = VTHp;               // 64..80MB
    u16* XqL = VTLp;               // 80..96MB
    u16* XkH = CTXH;               // 96..112MB
    u16* XkL = CTXL;               // 112..128MB
    u16* WqH = (u16*)(wsb + 128 * MB);
    u16* WqL = (u16*)(wsb + 130 * MB);
    u16* WkH = (u16*)(wsb + 132 * MB);
    u16* WkL = (u16*)(wsb + 134 * MB);
    u16* WvH = (u16*)(wsb + 136 * MB);
    u16* WvL = (u16*)(wsb + 138 * MB);
    u16* WoH = (u16*)(wsb + 128 * MB);   // written after attention loop
    u16* WoL = (u16*)(wsb + 130 * MB);

    // Adaptive bh-chunking (pure function of ws_size -> graph-capture safe).
    long s_cap_floats = (long)(ws_size / 4) - 33554432L;
    int chunk = 64;
    while (chunk > 1 && (long)chunk * (long)S_PER_BH > s_cap_floats) chunk >>= 1;

    dim3 blk(256);

    // Pre-split inputs and weights.
    split_f32<<<dim3(2048), blk, 0, stream>>>(q_in, XqH, XqL, 2097152);
    split_f32<<<dim3(2048), blk, 0, stream>>>(k_in, XkH, XkL, 2097152);
    split_f32<<<dim3(1024), blk, 0, stream>>>(Wq, WqH, WqL, 262144);
    split_f32<<<dim3(1024), blk, 0, stream>>>(Wk, WkH, WkL, 262144);
    split_f32<<<dim3(1024), blk, 0, stream>>>(Wv, WvH, WvL, 262144);

    // Projections (gemm V writes V^T directly; overwrites dead Xq region).
    gemm_mfma<<<dim3(8, 128), blk, 0, stream>>>(XqH, XqL, WqH, WqL, bq,
                                                nullptr, QHp, QLp, 0);
    gemm_mfma<<<dim3(8, 128), blk, 0, stream>>>(XkH, XkL, WkH, WkL, bk,
                                                nullptr, KHp, KLp, 0);
    gemm_mfma<<<dim3(8, 128), blk, 0, stream>>>(XkH, XkL, WvH, WvL, bv,
                                                nullptr, VTHp, VTLp, 1);

    for (int bh0 = 0; bh0 < NB * NH; bh0 += chunk) {
        scores_mfma<<<dim3(16, 16, chunk), blk, 0, stream>>>(QHp, QLp, KHp, KLp,
                                                             mask, S, bh0);
        softmax_topk<<<dim3(chunk * 512), blk, 0, stream>>>(S);
        av_mfma<<<dim3(64, chunk), dim3(512), 0, stream>>>((const unsigned int*)S,
                                                           VTHp, VTLp, QHp, QLp,
                                                           CTXH, CTXL, bh0);
    }

    // S region is dead now; split Wo there and run the output projection.
    split_f32<<<dim3(1024), blk, 0, stream>>>(Wo, WoH, WoL, 262144);
    gemm_mfma<<<dim3(8, 128), blk, 0, stream>>>(CTXH, CTXL, WoH, WoL, bo,
                                                out, nullptr, nullptr, 2);
}

// Round 11
// 1431.157 us; speedup vs baseline: 1.1277x; 1.1277x over previous
//
#include <hip/hip_runtime.h>
#include <math.h>

// Problem constants
#define NB   4        // batch
#define NH   16       // heads
#define DHD  64       // head dim
#define SL   2048     // Lq == Lk
#define DM   1024     // model dim
#define TOPK 205      // ceil(2048 * 0.1)

#define S_PER_BH 4194304   // 2048*2048 floats per (b,h) plane

// Scores are written in log2 domain: logit2 = (q.k) * 0.25 * log2(e).
#define SCALE_LOG2 0.36067376022224085f
#define MASK_LOG2  (-28853.900808f)

// ws layout (bytes), fixed part (identical to the measured round-4 kernel):
//  QH  bf16 head-major [B,H,L,DH] : 16MB @ 0
//  QL                              : 16MB @ 16MB
//  KH                              : 16MB @ 32MB
//  KL                              : 16MB @ 48MB
//  VTH bf16 transposed [B,H,DH,L]  : 16MB @ 64MB
//  VTL                             : 16MB @ 80MB
//  CTXH bf16 [B,L,D]               : 16MB @ 96MB
//  CTXL                            : 16MB @ 112MB
//  S   f32/packed [chunk,L,L]      : adaptive @ 128MB
// transient overlays (dead-region reuse, stream-ordered):
//  Xq split   -> 64..96MB  (consumed by gemm Q before gemm V writes VT)
//  Xk split   -> 96..128MB (consumed by gemm K/V before av writes CTX)
//  Wq/Wk/Wv   -> 128..140MB (consumed by gemms before scores writes S)
//  Wo split   -> 128..132MB (written AFTER attention loop, S is dead)

typedef unsigned short u16;
typedef short    bf16x8  __attribute__((ext_vector_type(8)));
typedef float    f32x4   __attribute__((ext_vector_type(4)));
typedef u16      ushort8 __attribute__((ext_vector_type(8)));
typedef u16      ushort4v __attribute__((ext_vector_type(4)));

// Round-to-nearest-even float -> bf16 split: x ~= hi + lo, both bf16.
__device__ inline void split2(float x, u16& h, u16& l)
{
    unsigned u = __float_as_uint(x);
    unsigned r = u + 0x7FFF + ((u >> 16) & 1);
    u16 hs = (u16)(r >> 16);
    float hf = __uint_as_float((unsigned)hs << 16);
    float lf = x - hf;
    unsigned ul = __float_as_uint(lf);
    unsigned rl = ul + 0x7FFF + ((ul >> 16) & 1);
    h = hs;
    l = (u16)(rl >> 16);
}

// ---------------------------------------------------------------------------
// Bulk fp32 -> split-bf16 conversion (one-time per tensor).
// ---------------------------------------------------------------------------
__global__ __launch_bounds__(256) void split_f32(const float* __restrict__ in,
                                                 u16* __restrict__ oh,
                                                 u16* __restrict__ ol,
                                                 int n4)
{
    const int stride = gridDim.x * 256;
    for (int i = blockIdx.x * 256 + threadIdx.x; i < n4; i += stride) {
        float4 v = ((const float4*)in)[i];
        u16 h0, l0, h1, l1, h2, l2, h3, l3;
        split2(v.x, h0, l0);
        split2(v.y, h1, l1);
        split2(v.z, h2, l2);
        split2(v.w, h3, l3);
        ushort4v h = { h0, h1, h2, h3 };
        ushort4v l = { l0, l1, l2, l3 };
        *(ushort4v*)&oh[(size_t)i * 4] = h;
        *(ushort4v*)&ol[(size_t)i * 4] = l;
    }
}

// ---------------------------------------------------------------------------
// Projection GEMM, pre-split operands: out = X @ W^T + bias.
// A = XH/XL [M,1024] u16 row-major; B = WH/WL [N,1024] u16 row-major.
// D += Ah*Bh + Ah*Bl + Al*Bh  (ll dropped; rel err ~2^-17).
// 128x128 tile, BK=32, 256 threads = 4 waves, each wave 64x64.
// (Round-10 tried 64x128 @ 1024 blocks: occupancy 18->32% but MfmaUtil
// DROPPED 24->21%, dur 87->99.7us -- barrier-drain fraction grew. The
// 128x128 tile is the better point for this 2-barrier loop; keep it.)
// XCD-aware chunked block swizzle (512 blocks % 8 == 0 -> bijective).
// mode 0: head-major split write; 1: tanh + transposed split write (V^T);
// mode 2: fp32 [M,N] write.
// ---------------------------------------------------------------------------
__global__ __launch_bounds__(256) void gemm_mfma(const u16* __restrict__ XH,
                                                 const u16* __restrict__ XL,
                                                 const u16* __restrict__ WH,
                                                 const u16* __restrict__ WL,
                                                 const float* __restrict__ bias,
                                                 float* __restrict__ outF,
                                                 u16* __restrict__ outH,
                                                 u16* __restrict__ outL,
                                                 int mode)
{
    __shared__ u16 Ah[128 * 40];
    __shared__ u16 Al[128 * 40];
    __shared__ u16 Bh[128 * 40];
    __shared__ u16 Bl[128 * 40];

    const int t    = threadIdx.x;
    const int lane = t & 63;
    const int wv   = t >> 6;
    const int wm   = (wv & 1) * 64;
    const int wn   = (wv >> 1) * 64;

    // XCD swizzle: give each XCD a contiguous run of m-panels for L2 reuse.
    const int lin  = blockIdx.x + (int)gridDim.x * blockIdx.y;   // 0..511
    const int per  = ((int)gridDim.x * (int)gridDim.y) >> 3;     // 64
    const int swz  = (lin & 7) * per + (lin >> 3);
    const int n0   = (swz & 7) * 128;       // gridDim.x == 8
    const int m0   = (swz >> 3) * 128;

    const int ra   = t >> 1;          // staging row 0..127
    const int ca   = (t & 1) * 16;    // staging col base 0/16

    const u16* XHp = XH + (size_t)(m0 + ra) * DM + ca;
    const u16* XLp = XL + (size_t)(m0 + ra) * DM + ca;
    const u16* WHp = WH + (size_t)(n0 + ra) * DM + ca;
    const u16* WLp = WL + (size_t)(n0 + ra) * DM + ca;

    f32x4 acc[4][4] = {};

    const int lm   = lane & 15;
    const int koff = (lane >> 4) * 8;

    for (int kb = 0; kb < DM; kb += 32) {
        ushort8 xh0 = *(const ushort8*)(XHp + kb);
        ushort8 xh1 = *(const ushort8*)(XHp + kb + 8);
        ushort8 xl0 = *(const ushort8*)(XLp + kb);
        ushort8 xl1 = *(const ushort8*)(XLp + kb + 8);
        ushort8 wh0 = *(const ushort8*)(WHp + kb);
        ushort8 wh1 = *(const ushort8*)(WHp + kb + 8);
        ushort8 wl0 = *(const ushort8*)(WLp + kb);
        ushort8 wl1 = *(const ushort8*)(WLp + kb + 8);
        __syncthreads();   // previous iteration's readers done
        *(ushort8*)&Ah[ra * 40 + ca]     = xh0;
        *(ushort8*)&Ah[ra * 40 + ca + 8] = xh1;
        *(ushort8*)&Al[ra * 40 + ca]     = xl0;
        *(ushort8*)&Al[ra * 40 + ca + 8] = xl1;
        *(ushort8*)&Bh[ra * 40 + ca]     = wh0;
        *(ushort8*)&Bh[ra * 40 + ca + 8] = wh1;
        *(ushort8*)&Bl[ra * 40 + ca]     = wl0;
        *(ushort8*)&Bl[ra * 40 + ca + 8] = wl1;
        __syncthreads();
        bf16x8 a_h[4], a_l[4], b_h[4], b_l[4];
        #pragma unroll
        for (int i = 0; i < 4; ++i) {
            int idx = (wm + i * 16 + lm) * 40 + koff;
            a_h[i] = *(const bf16x8*)&Ah[idx];
            a_l[i] = *(const bf16x8*)&Al[idx];
        }
        #pragma unroll
        for (int j = 0; j < 4; ++j) {
            int jdx = (wn + j * 16 + lm) * 40 + koff;
            b_h[j] = *(const bf16x8*)&Bh[jdx];
            b_l[j] = *(const bf16x8*)&Bl[jdx];
        }
        #pragma unroll
        for (int i = 0; i < 4; ++i)
            #pragma unroll
            for (int j = 0; j < 4; ++j) {
                acc[i][j] = __builtin_amdgcn_mfma_f32_16x16x32_bf16(
                    a_h[i], b_h[j], acc[i][j], 0, 0, 0);
                acc[i][j] = __builtin_amdgcn_mfma_f32_16x16x32_bf16(
                    a_h[i], b_l[j], acc[i][j], 0, 0, 0);
                acc[i][j] = __builtin_amdgcn_mfma_f32_16x16x32_bf16(
                    a_l[i], b_h[j], acc[i][j], 0, 0, 0);
            }
    }

    // ---- epilogue: C/D layout col=lane&15 (n), row=(lane>>4)*4+r (m) ----
    const int rq = (lane >> 4) * 4;
    #pragma unroll
    for (int j = 0; j < 4; ++j) {
        int n = n0 + wn + j * 16 + lm;
        float bb = bias[n];
        #pragma unroll
        for (int i = 0; i < 4; ++i) {
            #pragma unroll
            for (int r = 0; r < 4; ++r) {
                int m = m0 + wm + i * 16 + rq + r;
                float v = acc[i][j][r] + bb;
                if (mode == 2) {
                    outF[(size_t)m * DM + n] = v;
                } else {
                    int b = m >> 11, l = m & 2047, hh = n >> 6, d = n & 63;
                    size_t idx;
                    if (mode == 1) {
                        v = tanhf(v);
                        idx = ((size_t)(b * NH + hh) * DHD + d) * SL + l;   // V^T
                    } else {
                        idx = ((size_t)(b * NH + hh) * SL + l) * DHD + d;
                    }
                    u16 h_, l_;
                    split2(v, h_, l_);
                    outH[idx] = h_;
                    outL[idx] = l_;
                }
            }
        }
    }
}

// ---------------------------------------------------------------------------
// Scores via split-bf16 MFMA: S[z,q,k] = log2e*0.25 * Q.K ; masked -> -28854.
// (log2 domain so softmax can use native exp2.)
// 128x128 tile, full DH=64 as two BK=32 steps, grid (16,16,chunk).
// ---------------------------------------------------------------------------
__global__ __launch_bounds__(256) void scores_mfma(const u16* __restrict__ QH,
                                                   const u16* __restrict__ QL,
                                                   const u16* __restrict__ KH,
                                                   const u16* __restrict__ KL,
                                                   const int* __restrict__ mask,
                                                   float* __restrict__ S,
                                                   int bh0)
{
    __shared__ u16 Qhs[128 * 40];
    __shared__ u16 Qls[128 * 40];
    __shared__ u16 Khs[128 * 40];
    __shared__ u16 Kls[128 * 40];

    const int t    = threadIdx.x;
    const int lane = t & 63;
    const int wv   = t >> 6;
    const int wm   = (wv & 1) * 64;
    const int wn   = (wv >> 1) * 64;
    const int k0   = blockIdx.x * 128;
    const int q0   = blockIdx.y * 128;
    const int bhid = bh0 + blockIdx.z;

    const int row = t >> 1;          // 0..127
    const int col = (t & 1) * 16;    // 0/16
    const size_t qg = ((size_t)bhid * SL + q0 + row) * DHD + col;
    const size_t kg = ((size_t)bhid * SL + k0 + row) * DHD + col;

    f32x4 acc[4][4] = {};
    const int lm = lane & 15;
    const int ko = (lane >> 4) * 8;

    #pragma unroll
    for (int s = 0; s < 2; ++s) {
        ushort8 qh0 = *(const ushort8*)&QH[qg + s * 32];
        ushort8 qh1 = *(const ushort8*)&QH[qg + s * 32 + 8];
        ushort8 ql0 = *(const ushort8*)&QL[qg + s * 32];
        ushort8 ql1 = *(const ushort8*)&QL[qg + s * 32 + 8];
        ushort8 kh0 = *(const ushort8*)&KH[kg + s * 32];
        ushort8 kh1 = *(const ushort8*)&KH[kg + s * 32 + 8];
        ushort8 kl0 = *(const ushort8*)&KL[kg + s * 32];
        ushort8 kl1 = *(const ushort8*)&KL[kg + s * 32 + 8];
        __syncthreads();
        *(ushort8*)&Qhs[row * 40 + col]     = qh0;
        *(ushort8*)&Qhs[row * 40 + col + 8] = qh1;
        *(ushort8*)&Qls[row * 40 + col]     = ql0;
        *(ushort8*)&Qls[row * 40 + col + 8] = ql1;
        *(ushort8*)&Khs[row * 40 + col]     = kh0;
        *(ushort8*)&Khs[row * 40 + col + 8] = kh1;
        *(ushort8*)&Kls[row * 40 + col]     = kl0;
        *(ushort8*)&Kls[row * 40 + col + 8] = kl1;
        __syncthreads();
        bf16x8 ah[4], al[4], bh_[4], bl_[4];
        #pragma unroll
        for (int i = 0; i < 4; ++i) {
            int idx = (wm + i * 16 + lm) * 40 + ko;
            ah[i] = *(const bf16x8*)&Qhs[idx];
            al[i] = *(const bf16x8*)&Qls[idx];
        }
        #pragma unroll
        for (int j = 0; j < 4; ++j) {
            int jdx = (wn + j * 16 + lm) * 40 + ko;
            bh_[j] = *(const bf16x8*)&Khs[jdx];
            bl_[j] = *(const bf16x8*)&Kls[jdx];
        }
        #pragma unroll
        for (int i = 0; i < 4; ++i)
            #pragma unroll
            for (int j = 0; j < 4; ++j) {
                acc[i][j] = __builtin_amdgcn_mfma_f32_16x16x32_bf16(
                    ah[i], bh_[j], acc[i][j], 0, 0, 0);
                acc[i][j] = __builtin_amdgcn_mfma_f32_16x16x32_bf16(
                    ah[i], bl_[j], acc[i][j], 0, 0, 0);
                acc[i][j] = __builtin_amdgcn_mfma_f32_16x16x32_bf16(
                    al[i], bh_[j], acc[i][j], 0, 0, 0);
            }
    }

    const int rq = (lane >> 4) * 4;
    const int b  = bhid >> 4;
    const size_t zbase = (size_t)blockIdx.z * SL;
    #pragma unroll
    for (int j = 0; j < 4; ++j) {
        int k = k0 + wn + j * 16 + lm;
        int mk = mask[(size_t)b * SL + k];
        #pragma unroll
        for (int i = 0; i < 4; ++i) {
            #pragma unroll
            for (int r = 0; r < 4; ++r) {
                int q = q0 + wm + i * 16 + rq + r;
                float val = mk ? MASK_LOG2 : acc[i][j][r] * SCALE_LOG2;
                S[(zbase + q) * SL + k] = val;
            }
        }
    }
}

// ---------------------------------------------------------------------------
// Softmax (log2 domain, native exp2) + exact top-k threshold mask; writes
// packed split-bf16 (hi<<16|lo) in place over S.
// One row per wave; row cached in 32 VGPRs.  Bitwise binary search counts
// via ballot+popcount (count lands wave-uniform in SGPR).  EXACT early-exit:
// if cnt(v >= mid) == TOPK then {v >= mid} is precisely the reference top-k
// set ({v>=mid} superset of {v>=t}, equal sizes -> equal sets), so masking at
// mid is bit-identical to masking at the k-th largest value.  Expected
// iterations drop ~30 -> ~12 (exit once mid lands in the 205th/206th gap).
// ---------------------------------------------------------------------------
__global__ __launch_bounds__(256) void softmax_topk(float* __restrict__ S)
{
    const int wave = threadIdx.x >> 6;
    const int lane = threadIdx.x & 63;
    const size_t row = (size_t)blockIdx.x * 4 + wave;
    float4* Sr = (float4*)(S + row * SL);               // 512 float4

    float4 v[8];
    #pragma unroll
    for (int i = 0; i < 8; ++i) v[i] = Sr[lane + 64 * i];

    float m = -1e30f;
    #pragma unroll
    for (int i = 0; i < 8; ++i)
        m = fmaxf(m, fmaxf(fmaxf(v[i].x, v[i].y), fmaxf(v[i].z, v[i].w)));
    #pragma unroll
    for (int o = 32; o > 0; o >>= 1) m = fmaxf(m, __shfl_xor(m, o, 64));

    float sum = 0.0f;
    #pragma unroll
    for (int i = 0; i < 8; ++i) {
        v[i].x = exp2f(v[i].x - m); v[i].y = exp2f(v[i].y - m);
        v[i].z = exp2f(v[i].z - m); v[i].w = exp2f(v[i].w - m);
        sum += (v[i].x + v[i].y) + (v[i].z + v[i].w);
    }
    #pragma unroll
    for (int o = 32; o > 0; o >>= 1) sum += __shfl_xor(sum, o, 64);
    float inv = 1.0f / sum;
    #pragma unroll
    for (int i = 0; i < 8; ++i) {
        v[i].x *= inv; v[i].y *= inv; v[i].z *= inv; v[i].w *= inv;
    }

    unsigned lo = 0u, hi = __float_as_uint(inv);
    while (lo < hi) {
        unsigned mid = (lo + hi + 1u) >> 1;
        int cnt = 0;
        #pragma unroll
        for (int i = 0; i < 8; ++i) {
            cnt += (int)__popcll(__ballot(__float_as_uint(v[i].x) >= mid));
            cnt += (int)__popcll(__ballot(__float_as_uint(v[i].y) >= mid));
            cnt += (int)__popcll(__ballot(__float_as_uint(v[i].z) >= mid));
            cnt += (int)__popcll(__ballot(__float_as_uint(v[i].w) >= mid));
        }
        if (cnt >= TOPK) {
            lo = mid;
            if (cnt == TOPK) break;   // exact (see header comment)
        } else {
            hi = mid - 1u;
        }
    }

    #pragma unroll
    for (int i = 0; i < 8; ++i) {
        float4 x = v[i];
        x.x = (__float_as_uint(x.x) >= lo) ? x.x : 0.0f;
        x.y = (__float_as_uint(x.y) >= lo) ? x.y : 0.0f;
        x.z = (__float_as_uint(x.z) >= lo) ? x.z : 0.0f;
        x.w = (__float_as_uint(x.w) >= lo) ? x.w : 0.0f;
        u16 h_, l_;
        uint4 pk;
        split2(x.x, h_, l_); pk.x = ((unsigned)h_ << 16) | l_;
        split2(x.y, h_, l_); pk.y = ((unsigned)h_ << 16) | l_;
        split2(x.z, h_, l_); pk.z = ((unsigned)h_ << 16) | l_;
        split2(x.w, h_, l_); pk.w = ((unsigned)h_ << 16) | l_;
        *(uint4*)&Sr[lane + 64 * i] = pk;
    }
}

// ---------------------------------------------------------------------------
// AV via split-bf16 MFMA: CTX[b,q,h*64+d] = (sum_k attn*V) * gate(Q).
// 512 threads = 8 waves; block = 32q x 64d, each wave 16q x 16d; BK=64.
// Output written pre-split (CTXH/CTXL) for the Wo GEMM.
// ---------------------------------------------------------------------------
__global__ __launch_bounds__(512) void av_mfma(const unsigned int* __restrict__ SA,
                                               const u16* __restrict__ VTH,
                                               const u16* __restrict__ VTL,
                                               const u16* __restrict__ QH,
                                               const u16* __restrict__ QL,
                                               u16* __restrict__ CTXH,
                                               u16* __restrict__ CTXL,
                                               int bh0)
{
    __shared__ u16 Ahs[32 * 72];
    __shared__ u16 Als[32 * 72];
    __shared__ u16 Bhs[64 * 72];
    __shared__ u16 Bls[64 * 72];

    const int t    = threadIdx.x;
    const int lane = t & 63;
    const int wv   = t >> 6;          // 0..7
    const int wm   = (wv & 1) * 16;   // q sub-tile 0/16
    const int wn   = (wv >> 1) * 16;  // d sub-tile 0/16/32/48
    const int q0   = blockIdx.x * 32;
    const int z    = blockIdx.y;
    const int bhid = bh0 + z;
    const int b    = bhid >> 4, hh = bhid & 15;

    const int arow = t >> 4;          // 0..31 (q)
    const int acol = (t & 15) * 4;    // 0..60 (k, u32 granules)
    const int brow = t >> 3;          // 0..63 (d)
    const int bcol = (t & 7) * 8;     // 0..56 (k)

    const unsigned int* Sp = SA + ((size_t)z * SL + q0 + arow) * SL + acol;
    const u16* Vhp = VTH + ((size_t)bhid * DHD + brow) * SL + bcol;
    const u16* Vlp = VTL + ((size_t)bhid * DHD + brow) * SL + bcol;

    const int lm = lane & 15;
    const int ko = (lane >> 4) * 8;

    f32x4 acc = {};

    for (int kb = 0; kb < SL; kb += 64) {
        uint4 ua = *(const uint4*)(Sp + kb);
        ushort8 vh = *(const ushort8*)(Vhp + kb);
        ushort8 vl = *(const ushort8*)(Vlp + kb);
        __syncthreads();   // previous iteration's readers done
        ushort4v h0 = { (u16)(ua.x >> 16), (u16)(ua.y >> 16),
                        (u16)(ua.z >> 16), (u16)(ua.w >> 16) };
        ushort4v l0 = { (u16)ua.x, (u16)ua.y, (u16)ua.z, (u16)ua.w };
        *(ushort4v*)&Ahs[arow * 72 + acol] = h0;
        *(ushort4v*)&Als[arow * 72 + acol] = l0;
        *(ushort8*)&Bhs[brow * 72 + bcol]  = vh;
        *(ushort8*)&Bls[brow * 72 + bcol]  = vl;
        __syncthreads();
        #pragma unroll
        for (int s = 0; s < 2; ++s) {
            int ao = (wm + lm) * 72 + s * 32 + ko;
            bf16x8 a_h = *(const bf16x8*)&Ahs[ao];
            bf16x8 a_l = *(const bf16x8*)&Als[ao];
            int bo = (wn + lm) * 72 + s * 32 + ko;
            bf16x8 b_h = *(const bf16x8*)&Bhs[bo];
            bf16x8 b_l = *(const bf16x8*)&Bls[bo];
            acc = __builtin_amdgcn_mfma_f32_16x16x32_bf16(a_h, b_h, acc, 0, 0, 0);
            acc = __builtin_amdgcn_mfma_f32_16x16x32_bf16(a_h, b_l, acc, 0, 0, 0);
            acc = __builtin_amdgcn_mfma_f32_16x16x32_bf16(a_l, b_h, acc, 0, 0, 0);
        }
    }

    const int rq = (lane >> 4) * 4;
    const int d  = wn + lm;
    #pragma unroll
    for (int r = 0; r < 4; ++r) {
        int q = q0 + wm + rq + r;
        size_t gi = ((size_t)bhid * SL + q) * DHD + d;
        float gf = __uint_as_float((unsigned)QH[gi] << 16)
                 + __uint_as_float((unsigned)QL[gi] << 16);
        float cv = acc[r] * gf;
        u16 h_, l_;
        split2(cv, h_, l_);
        size_t ci = ((size_t)b * SL + q) * DM + hh * DHD + d;
        CTXH[ci] = h_;
        CTXL[ci] = l_;
    }
}

// ---------------------------------------------------------------------------
extern "C" void kernel_launch(void* const* d_in, const int* in_sizes, int n_in,
                              void* d_out, int out_size, void* d_ws, size_t ws_size,
                              hipStream_t stream)
{
    const float* q_in = (const float*)d_in[0];
    const float* k_in = (const float*)d_in[1];
    const float* Wq   = (const float*)d_in[2];
    const float* bq   = (const float*)d_in[3];
    const float* Wk   = (const float*)d_in[4];
    const float* bk   = (const float*)d_in[5];
    const float* Wv   = (const float*)d_in[6];
    const float* bv   = (const float*)d_in[7];
    const float* Wo   = (const float*)d_in[8];
    const float* bo   = (const float*)d_in[9];
    const int*   mask = (const int*)d_in[10];   // bool -> int32 per harness
    float* out = (float*)d_out;

    char* wsb = (char*)d_ws;
    const size_t MB = 1024 * 1024;
    u16* QHp  = (u16*)(wsb);
    u16* QLp  = (u16*)(wsb + 16 * MB);
    u16* KHp  = (u16*)(wsb + 32 * MB);
    u16* KLp  = (u16*)(wsb + 48 * MB);
    u16* VTHp = (u16*)(wsb + 64 * MB);
    u16* VTLp = (u16*)(wsb + 80 * MB);
    u16* CTXH = (u16*)(wsb + 96 * MB);
    u16* CTXL = (u16*)(wsb + 112 * MB);
    float* S  = (float*)(wsb + 128 * MB);

    // Transient overlays (see layout comment).
    u16* XqH = VTHp;               // 64..80MB
    u16* XqL = VTLp;               // 80..96MB
    u16* XkH = CTXH;               // 96..112MB
    u16* XkL = CTXL;               // 112..128MB
    u16* WqH = (u16*)(wsb + 128 * MB);
    u16* WqL = (u16*)(wsb + 130 * MB);
    u16* WkH = (u16*)(wsb + 132 * MB);
    u16* WkL = (u16*)(wsb + 134 * MB);
    u16* WvH = (u16*)(wsb + 136 * MB);
    u16* WvL = (u16*)(wsb + 138 * MB);
    u16* WoH = (u16*)(wsb + 128 * MB);   // written after attention loop
    u16* WoL = (u16*)(wsb + 130 * MB);

    // Adaptive bh-chunking (pure function of ws_size -> graph-capture safe).
    long s_cap_floats = (long)(ws_size / 4) - 33554432L;
    int chunk = 64;
    while (chunk > 1 && (long)chunk * (long)S_PER_BH > s_cap_floats) chunk >>= 1;

    dim3 blk(256);

    // Pre-split inputs and weights.
    split_f32<<<dim3(2048), blk, 0, stream>>>(q_in, XqH, XqL, 2097152);
    split_f32<<<dim3(2048), blk, 0, stream>>>(k_in, XkH, XkL, 2097152);
    split_f32<<<dim3(1024), blk, 0, stream>>>(Wq, WqH, WqL, 262144);
    split_f32<<<dim3(1024), blk, 0, stream>>>(Wk, WkH, WkL, 262144);
    split_f32<<<dim3(1024), blk, 0, stream>>>(Wv, WvH, WvL, 262144);

    // Projections (gemm V writes V^T directly; overwrites dead Xq region).
    gemm_mfma<<<dim3(8, 64), blk, 0, stream>>>(XqH, XqL, WqH, WqL, bq,
                                               nullptr, QHp, QLp, 0);
    gemm_mfma<<<dim3(8, 64), blk, 0, stream>>>(XkH, XkL, WkH, WkL, bk,
                                               nullptr, KHp, KLp, 0);
    gemm_mfma<<<dim3(8, 64), blk, 0, stream>>>(XkH, XkL, WvH, WvL, bv,
                                               nullptr, VTHp, VTLp, 1);

    for (int bh0 = 0; bh0 < NB * NH; bh0 += chunk) {
        scores_mfma<<<dim3(16, 16, chunk), blk, 0, stream>>>(QHp, QLp, KHp, KLp,
                                                             mask, S, bh0);
        softmax_topk<<<dim3(chunk * 512), blk, 0, stream>>>(S);
        av_mfma<<<dim3(64, chunk), dim3(512), 0, stream>>>((const unsigned int*)S,
                                                           VTHp, VTLp, QHp, QLp,
                                                           CTXH, CTXL, bh0);
    }

    // S region is dead now; split Wo there and run the output projection.
    split_f32<<<dim3(1024), blk, 0, stream>>>(Wo, WoH, WoL, 262144);
    gemm_mfma<<<dim3(8, 64), blk, 0, stream>>>(CTXH, CTXL, WoH, WoL, bo,
                                               out, nullptr, nullptr, 2);
}